// Round 10
// baseline (186.360 us; speedup 1.0000x reference)
//
#include <hip/hip_runtime.h>
#include <hip/hip_bf16.h>
#include <math.h>

// MultiHeadSelfAttention: B=2,S=2048,D=1024,H=16,hd=64, fp32 in/out.
// bf16 MFMA everywhere; flash attention (S^T form) with no-max softmax.
// R21 = R20 resubmit (container infra failure, kernel never ran).
// R20 = R19 + bijective XCD swizzle on both gemm_bt grids (T1).
// Default dispatch round-robins linear wg id across 8 XCDs -> blocks sharing
// an A row-panel land on different L2s. Swizzle swz=(lid&7)*q+lid/8 gives
// each XCD 4 contiguous M-bands x all N: per-XCD L2 set = 1MB A + full B.
// nwg=768/512 both %8==0 -> clean bijection (ERRATA #11). GX templated so
// div/mod fold to magic-mul constants.
// R19 ledger: gemm (256,4) + V^T uint2 store: 189.5 -> 185.3us. attn frozen
// at R12 optimum (52.2us): kv-split WIN; ping-pong x2, setprio, cvt_pk all
// measured FAIL. BANK_CONFLICT 4.19M = intrinsic b128 cost.

typedef __bf16 bf16_t;
typedef __bf16 bf16x8 __attribute__((ext_vector_type(8)));
typedef float f32x4 __attribute__((ext_vector_type(4)));
typedef float f32x16 __attribute__((ext_vector_type(16)));
typedef unsigned u32x2 __attribute__((ext_vector_type(2)));

#define B_ 2
#define S_ 2048
#define D_ 1024
#define H_ 16
#define HD_ 64
// fold softmax scale (1/8) * log2(e) into Q so scores feed exp2 directly
#define QSCALE 0.18033688011112042f

__device__ __forceinline__ void load_lds16(const void* g, void* s) {
  // direct global->LDS DMA, 16B/lane; LDS dest is wave-uniform base + lane*16
  __builtin_amdgcn_global_load_lds((__attribute__((address_space(1))) unsigned int*)g,
                                   (__attribute__((address_space(3))) unsigned int*)s,
                                   16, 0, 0);
}

// fast fp32->bf16: round-to-nearest via +0x8000 (no NaN path; inputs finite).
__device__ __forceinline__ bf16_t fbf16(float x) {
  unsigned u = (__builtin_bit_cast(unsigned, x) + 0x8000u) >> 16;
  unsigned short s = (unsigned short)u;
  return __builtin_bit_cast(bf16_t, s);
}
// pack two fp32 -> bf16x2 in one v_perm_b32: result = {hi16(ub),hi16(ua)}
__device__ __forceinline__ unsigned pack_bf16x2(float a, float b) {
  unsigned ua = __builtin_bit_cast(unsigned, a) + 0x8000u;
  unsigned ub = __builtin_bit_cast(unsigned, b) + 0x8000u;
  return __builtin_amdgcn_perm(ub, ua, 0x07060302u);
}

// ---------------- fused fp32 -> bf16 convert (x, w_qkv, w_proj) ----------------
__global__ void tobf16_all(const float* __restrict__ x, const float* __restrict__ wq,
                           const float* __restrict__ wp, bf16_t* __restrict__ xb,
                           bf16_t* __restrict__ wqb, bf16_t* __restrict__ wpb) {
  int bid = blockIdx.x;
  const float* in;
  bf16_t* out;
  int base;
  if (bid < 4096) { in = x; out = xb; base = bid; }
  else if (bid < 7168) { in = wq; out = wqb; base = bid - 4096; }
  else { in = wp; out = wpb; base = bid - 7168; }
  int i = base * 256 + threadIdx.x;  // all three sizes are exact multiples of 256 float4
  float4 v = ((const float4*)in)[i];
  uint2 o;
  o.x = pack_bf16x2(v.x, v.y);
  o.y = pack_bf16x2(v.z, v.w);
  ((uint2*)out)[i] = o;
}

// ---------------- GEMM: C[M,N] = A[M,K] @ B[N,K]^T + bias ----------------
// 128xBN tile, BK=32, 256 threads (4 waves 2x2), double-buffered, one barrier
// per k-iter (drains DMA issued a full iter earlier). 16B-unit XOR swizzle.
// EPI=0: QKV epilogue (scatter to q/k/vT bf16 layouts, q pre-scaled), BN=128
// EPI=1: proj epilogue (fp32 out), BN=64 for 2x grid
// launch_bounds (256,4): 4 blocks/CU. GX = gridDim.x (compile-time) for the
// XCD swizzle's div/mod to fold to magic-mul. Grid y is 32 in both uses.
template <int EPI, int BN, int GX>
__global__ __launch_bounds__(256, 4) void gemm_bt(
    const bf16_t* __restrict__ A, const bf16_t* __restrict__ Bm,
    const float* __restrict__ bias,
    bf16_t* __restrict__ qb, bf16_t* __restrict__ kb, bf16_t* __restrict__ vtb,
    float* __restrict__ outf) {
  constexpr int NI = BN / 32;            // n-fragments per wave
  constexpr int BUF = 8192 + BN * 64;    // bytes per buffer: A 8 KB + B BN*64
  constexpr int NWG = GX * 32;           // total workgroups (multiple of 8)
  constexpr int QX = NWG / 8;            // wgs per XCD
  __shared__ __align__(16) char smem[2 * BUF];
  const int tid = threadIdx.x;
  const int w = tid >> 6, lane = tid & 63;
  const int wm = w >> 1, wn = w & 1;
  const int quad = lane >> 4, l15 = lane & 15;
  // XCD swizzle: lid%8 = XCD (HW round-robin); give XCD g the contiguous
  // output range [g*QX, (g+1)*QX) -> 4 full M-bands x all N per XCD.
  const int lid = blockIdx.y * GX + blockIdx.x;
  const int swz = (lid & 7) * QX + (lid >> 3);
  const int m0 = (swz / GX) * 128, n0 = (swz % GX) * BN;

  auto stage = [&](int kt, int bb) {
    char* bA = smem + bb * BUF;
    char* bB = bA + 8192;
#pragma unroll
    for (int i = 0; i < 2; i++) {  // A: 512 units
      int ub = w * 128 + i * 64;
      int u = ub + lane;
      int r = u >> 2, c = (u & 3) ^ ((r >> 1) & 3);
      load_lds16(A + (size_t)(m0 + r) * 1024 + kt + c * 8, bA + (size_t)ub * 16);
    }
#pragma unroll
    for (int i = 0; i < BN / 64; i++) {  // B: BN*4 units
      int ub = w * (BN / 64) * 64 + i * 64;
      int u = ub + lane;
      int r = u >> 2, c = (u & 3) ^ ((r >> 1) & 3);
      load_lds16(Bm + (size_t)(n0 + r) * 1024 + kt + c * 8, bB + (size_t)ub * 16);
    }
  };

  f32x4 acc[4][NI];
#pragma unroll
  for (int mi = 0; mi < 4; mi++)
#pragma unroll
    for (int ni = 0; ni < NI; ni++) acc[mi][ni] = (f32x4){0.f, 0.f, 0.f, 0.f};

  stage(0, 0);  // prologue

  for (int it = 0; it < 32; it++) {
    __syncthreads();  // drains buf-it DMA (issued a full iter ago) + reuse sync
    if (it < 31) stage((it + 1) * 32, (it + 1) & 1);
    const bf16_t* bA = (const bf16_t*)(smem + (it & 1) * BUF);
    const bf16_t* bB = (const bf16_t*)(smem + (it & 1) * BUF + 8192);

    bf16x8 af[4], bfr[NI];
#pragma unroll
    for (int mi = 0; mi < 4; mi++) {
      int r = wm * 64 + mi * 16 + l15;
      af[mi] = *(const bf16x8*)(bA + (r * 4 + (quad ^ ((r >> 1) & 3))) * 8);
    }
#pragma unroll
    for (int ni = 0; ni < NI; ni++) {
      int r = wn * (BN / 2) + ni * 16 + l15;
      bfr[ni] = *(const bf16x8*)(bB + (r * 4 + (quad ^ ((r >> 1) & 3))) * 8);
    }
#pragma unroll
    for (int mi = 0; mi < 4; mi++)
#pragma unroll
      for (int ni = 0; ni < NI; ni++)
        acc[mi][ni] = __builtin_amdgcn_mfma_f32_16x16x32_bf16(af[mi], bfr[ni], acc[mi][ni], 0, 0, 0);
  }

  // epilogue: C row = m0+wm*64+mi*16+quad*4+r, col = n0+wn*(BN/2)+ni*16+l15
#pragma unroll
  for (int mi = 0; mi < 4; mi++) {
#pragma unroll
    for (int ni = 0; ni < NI; ni++) {
      int n = n0 + wn * (BN / 2) + ni * 16 + l15;
      float bv = bias[n];
      int mrow = m0 + wm * 64 + mi * 16 + quad * 4;  // 4 consecutive m
      if (EPI == 0) {
        int t = n >> 10;           // 0=Q,1=K,2=V (uniform per block: 128 | 1024)
        int rr = n & 1023;
        int hh = rr >> 6, d = rr & 63;
        int bb = mrow >> 11, s = mrow & 2047;  // all 4 rows share bb (m0%128==0)
        size_t bh = (size_t)(bb * H_ + hh);
        if (t == 2) {
          // V^T: per lane, 4 consecutive s at fixed d -> one 8B store
          uint2 o;
          o.x = pack_bf16x2(acc[mi][ni][0] + bv, acc[mi][ni][1] + bv);
          o.y = pack_bf16x2(acc[mi][ni][2] + bv, acc[mi][ni][3] + bv);
          *(uint2*)(vtb + (bh * HD_ + d) * S_ + s) = o;
        } else if (t == 0) {
#pragma unroll
          for (int r = 0; r < 4; r++)
            qb[(bh * S_ + s + r) * HD_ + d] = fbf16((acc[mi][ni][r] + bv) * QSCALE);
        } else {
#pragma unroll
          for (int r = 0; r < 4; r++)
            kb[(bh * S_ + s + r) * HD_ + d] = fbf16(acc[mi][ni][r] + bv);
        }
      } else {
#pragma unroll
        for (int r = 0; r < 4; r++)
          outf[(size_t)(mrow + r) * 1024 + n] = acc[mi][ni][r] + bv;
      }
    }
  }
}

// ---------------- flash attention (S^T form, kv-split, 2-stage pipelined) -------
// 1D grid of 1024; gid%8 = XCD: XCD g owns bh in [4g,4g+4) -> 2 MB K/V per XCD.
// block = (b,h, q-tile 64), 256 threads = 4 waves:
//   wave w: q-band (w&1)*32, kv-half (w>>1)*1024.  Each pair (waves 2p,2p+1)
//   runs its own dbuf pipeline over 32 kv-tiles of 32 (16 KB LDS per pair).
// S^T = K Q^T: A = K rows (m=kv 0..31, LDS), B = Q rows (n=q, regs).
// C/D 32x32: col=lane&31=q, row=kv=(reg&3)+8*(reg>>2)+4*h2  [m74/m101 layout].
// PIPELINE: iter j holds S_cur=S(j); av(j) read PRE-barrier (protects regs
// from stage(j+2) -> buf j&1), then barrier, stage(j+2), ak(j+1) reads +
// S(j+1) MFMAs | softmax(j) | PV(j). Single body, s_cur=s_next copy (~16
// v_mov, measured cheaper than every alternative tried).
// Max-free softmax => pair partials (O^T, l) combine by addition via LDS.
__global__ __launch_bounds__(256, 4) void attn(
    const bf16_t* __restrict__ qb, const bf16_t* __restrict__ kb,
    const bf16_t* __restrict__ vtb, bf16_t* __restrict__ ob) {
  __shared__ __align__(16) char smem[32768];
  const int tid = threadIdx.x, w = tid >> 6, lane = tid & 63;
  const int h2 = lane >> 5, l31 = lane & 31;
  const int qband = w & 1, pair = w >> 1;
  // XCD-aware decode: gid%8 = XCD; 4 bh x 32 q-tiles per XCD.
  const int gid = blockIdx.x;
  const int g = gid & 7, k_ = gid >> 3;
  const int bh = g * 4 + (k_ >> 5);
  const int qt = k_ & 31;
  const int b = bh >> 4, h = bh & 15;
  const size_t base = (size_t)bh * S_ * HD_;
  const size_t vbase = (size_t)bh * HD_ * S_;
  const int q0 = qt * 64;
  const int myq = q0 + qband * 32 + l31;  // this lane's q column
  const int kvbase = pair << 10;          // this wave's kv-half
  char* pbase = smem + pair * 16384;      // per-pair LDS: 2 bufs x (K 4K | V 4K)

  // Q B-frags (loop-invariant): B[n=q=l31][k=ks*16+h2*8+j]
  bf16x8 bq[4];
#pragma unroll
  for (int ks = 0; ks < 4; ks++)
    bq[ks] = *(const bf16x8*)(qb + base + (size_t)myq * 64 + ks * 16 + h2 * 8);

  // stage K[32 kv x 64 d] + V^T[64 d x 32 kv] into pair buffer bb.
  // K rows: 8 units/row, sigma(r)=r&7. V rows: 4 units/row, sigma(r)=(r>>1)&3.
  auto stage = [&](int kv0, int bb) {
    char* bK = pbase + bb * 8192;
    char* bV = bK + 4096;
#pragma unroll
    for (int i = 0; i < 2; i++) {
      int ub = qband * 64 + i * 128;
      int u = ub + lane;
      {
        int r = u >> 3, c = (u & 7) ^ (r & 7);
        load_lds16(kb + base + (size_t)(kv0 + r) * 64 + c * 8, bK + (size_t)ub * 16);
      }
      {
        int r = u >> 2, c = (u & 3) ^ ((r >> 1) & 3);
        load_lds16(vtb + vbase + (size_t)r * S_ + kv0 + c * 8, bV + (size_t)ub * 16);
      }
    }
  };

  f32x16 acc_o[2];
#pragma unroll
  for (int dt = 0; dt < 2; dt++)
#pragma unroll
    for (int i = 0; i < 16; i++) acc_o[dt][i] = 0.f;
  float l_acc = 0.f;  // per-lane: sum of p over this lane's kv rows, for q=myq

  // prologue: tile 0 staged+drained; tile 1 DMA in flight; s_cur = S(0)
  stage(kvbase, 0);
  __syncthreads();
  stage(kvbase + 32, 1);
  f32x16 s_cur;
  {
    const bf16_t* bK = (const bf16_t*)pbase;
#pragma unroll
    for (int i = 0; i < 16; i++) s_cur[i] = 0.f;
#pragma unroll
    for (int ks = 0; ks < 4; ks++) {
      int r = l31, c = ks * 2 + h2;
      bf16x8 ak = *(const bf16x8*)(bK + (r * 8 + (c ^ (r & 7))) * 8);
      s_cur = __builtin_amdgcn_mfma_f32_32x32x16_bf16(ak, bq[ks], s_cur, 0, 0, 0);
    }
  }

  for (int j = 0; j < 32; j++) {
    // V^T(j) A-frags PRE-barrier: tile j was drained at the previous barrier;
    // regs protect against stage(j+2) overwriting buf j&1 mid-iter.
    const bf16_t* bV = (const bf16_t*)(pbase + (j & 1) * 8192 + 4096);
    bf16x8 av[2][2];
#pragma unroll
    for (int ks = 0; ks < 2; ks++)
#pragma unroll
      for (int dt = 0; dt < 2; dt++) {
        int r = dt * 32 + l31, c = ks * 2 + h2;
        av[dt][ks] = *(const bf16x8*)(bV + (r * 4 + (c ^ ((r >> 1) & 3))) * 8);
      }

    __syncthreads();  // drains stage(j+1) DMA; all waves' av(j)/ak(j) reads done
    if (j < 30) stage(kvbase + (j + 2) * 32, j & 1);

    // S(j+1) = K(j+1) Q^T — independent of softmax(j) and PV(j)
    f32x16 s_next;
    if (j < 31) {
      const bf16_t* bK1 = (const bf16_t*)(pbase + ((j + 1) & 1) * 8192);
#pragma unroll
      for (int i = 0; i < 16; i++) s_next[i] = 0.f;
#pragma unroll
      for (int ks = 0; ks < 4; ks++) {
        int r = l31, c = ks * 2 + h2;
        bf16x8 ak = *(const bf16x8*)(bK1 + (r * 8 + (c ^ (r & 7))) * 8);
        s_next = __builtin_amdgcn_mfma_f32_32x32x16_bf16(ak, bq[ks], s_next, 0, 0, 0);
      }
    }

    // no-max softmax on s_cur (native exp2) + pack reg-pairs (adjacent kv)
    unsigned pk[8];
    float ls = 0.f;
#pragma unroll
    for (int i = 0; i < 8; i++) {
      float p0 = __builtin_amdgcn_exp2f(s_cur[2 * i]);
      float p1 = __builtin_amdgcn_exp2f(s_cur[2 * i + 1]);
      ls += p0 + p1;
      pk[i] = pack_bf16x2(p0, p1);
    }
    l_acc += ls;

    // build P^T B-frags: per 16-kv step, exchange packs across lane-halves.
    // permlane32_swap(a,b): dst0 = {a_lo | b_lo->hi}, dst1 = {a_hi->lo | b_hi}
    bf16x8 bp[2];
#pragma unroll
    for (int kk = 0; kk < 2; kk++) {
      unsigned a0 = pk[kk * 4 + 0], a1 = pk[kk * 4 + 1];
      unsigned a2 = pk[kk * 4 + 2], a3 = pk[kk * 4 + 3];
      u32x2 r02 = __builtin_amdgcn_permlane32_swap(a0, a2, false, false);
      u32x2 r13 = __builtin_amdgcn_permlane32_swap(a1, a3, false, false);
      union { unsigned u[4]; bf16x8 v; } bb;
      bb.u[0] = r02[0];
      bb.u[1] = r13[0];
      bb.u[2] = r02[1];
      bb.u[3] = r13[1];
      bp[kk] = bb.v;
    }

    // O^T += V^T(j) P^T(j)
#pragma unroll
    for (int ks = 0; ks < 2; ks++)
#pragma unroll
      for (int dt = 0; dt < 2; dt++)
        acc_o[dt] = __builtin_amdgcn_mfma_f32_32x32x16_bf16(av[dt][ks], bp[ks], acc_o[dt], 0, 0, 0);

    if (j < 31) s_cur = s_next;
  }

  // within-pair denominator: lane + h2-partner cover all kv rows of this half
  float l_pair = l_acc + (float)__shfl_xor(l_acc, 32);

  // cross-pair combine via LDS (K/V buffers dead after last in-loop barrier).
  // stride 33 floats -> conflict-free. Region: 2 qbands x 64 lanes x 33 f32.
  float* red = (float*)smem;
  const int rbase = qband * (64 * 33) + lane * 33;
  if (pair == 1) {
#pragma unroll
    for (int dt = 0; dt < 2; dt++)
#pragma unroll
      for (int i = 0; i < 16; i++) red[rbase + dt * 16 + i] = acc_o[dt][i];
    red[rbase + 32] = l_pair;
  }
  __syncthreads();
  if (pair == 0) {
#pragma unroll
    for (int dt = 0; dt < 2; dt++)
#pragma unroll
      for (int i = 0; i < 16; i++) acc_o[dt][i] += red[rbase + dt * 16 + i];
    float inv = 1.0f / (l_pair + red[rbase + 32]);

    // epilogue: O^T col q = myq (lane), rows d = dt*32 + 8*g4 + 4*h2 + (0..3)
#pragma unroll
    for (int dt = 0; dt < 2; dt++)
#pragma unroll
      for (int g4 = 0; g4 < 4; g4++) {
        uint2 o;
        o.x = pack_bf16x2(acc_o[dt][g4 * 4 + 0] * inv, acc_o[dt][g4 * 4 + 1] * inv);
        o.y = pack_bf16x2(acc_o[dt][g4 * 4 + 2] * inv, acc_o[dt][g4 * 4 + 3] * inv);
        int d = dt * 32 + g4 * 8 + h2 * 4;
        *(uint2*)(ob + ((size_t)b * S_ + myq) * D_ + h * HD_ + d) = o;
      }
  }
}

// ---------------- launcher ----------------
extern "C" void kernel_launch(void* const* d_in, const int* in_sizes, int n_in,
                              void* d_out, int out_size, void* d_ws, size_t ws_size,
                              hipStream_t stream) {
  const float* x = (const float*)d_in[0];        // [2,2048,1024]
  const float* w_qkv = (const float*)d_in[1];    // [3072,1024]
  const float* b_qkv = (const float*)d_in[2];    // [3072]
  const float* w_proj = (const float*)d_in[3];   // [1024,1024]
  const float* b_proj = (const float*)d_in[4];   // [1024]
  float* out = (float*)d_out;

  char* ws = (char*)d_ws;
  size_t off = 0;
  bf16_t* xb = (bf16_t*)(ws + off); off += (size_t)4096 * 1024 * 2;    // 8 MB
  bf16_t* wqkvb = (bf16_t*)(ws + off); off += (size_t)3072 * 1024 * 2; // 6 MB
  bf16_t* wpb = (bf16_t*)(ws + off); off += (size_t)1024 * 1024 * 2;   // 2 MB
  bf16_t* qb = (bf16_t*)(ws + off); off += (size_t)4096 * 1024 * 2;    // 8 MB [B,H,S,hd]
  bf16_t* kb = (bf16_t*)(ws + off); off += (size_t)4096 * 1024 * 2;    // 8 MB [B,H,S,hd]
  bf16_t* vtb = (bf16_t*)(ws + off); off += (size_t)4096 * 1024 * 2;   // 8 MB [B,H,hd,S]
  bf16_t* ob = xb;  // xb dead after QKV GEMM; reuse for attention output
  // total ws use: 41,943,040 B

  tobf16_all<<<8192, 256, 0, stream>>>(x, w_qkv, w_proj, xb, wqkvb, wpb);
  gemm_bt<0, 128, 24><<<dim3(24, 32), 256, 0, stream>>>(xb, wqkvb, b_qkv, qb, kb, vtb, nullptr);
  attn<<<1024, 256, 0, stream>>>(qb, kb, vtb, ob);
  gemm_bt<1, 64, 16><<<dim3(16, 32), 256, 0, stream>>>(ob, wpb, b_proj, nullptr, nullptr, nullptr, out);
}

// Round 11
// 183.569 us; speedup vs baseline: 1.0152x; 1.0152x over previous
//
#include <hip/hip_runtime.h>
#include <hip/hip_bf16.h>
#include <math.h>

// MultiHeadSelfAttention: B=2,S=2048,D=1024,H=16,hd=64, fp32 in/out.
// bf16 MFMA everywhere; flash attention (S^T form) with no-max softmax.
// R22 = R19 base (best measured 185.3us; R21's XCD swizzle was neutral ->
// dropped) + triple-buffered counted-vmcnt K-loop in gemm_bt (T4 at tile
// granularity):
//   per iter: s_waitcnt vmcnt(L) [drains stage(it), leaves stage(it+1) in
//   flight -> each stage gets ~2 iters of latency cover] ; s_barrier [every
//   wave drained its own slice -> tile it fully resident] ; stage(it+2)
//   [into buffer freed at iter it-1, ordered post-barrier] ; ds_read+MFMA.
//   Tail peeled: iter 31 uses vmcnt(0) (only stage(31) outstanding there --
//   vmcnt(L) would be a no-op race). L=4 for BN=128, 3 for BN=64.
// This removes the __syncthreads-implicit vmcnt(0) drain of just-issued
// loads (the m97-structure's ~20% barrier stall). LDS 3x16KB/3x12KB -> 3
// blocks/CU (was 4): the co-residency we lose was hiding the stall we
// remove.
// Ledger: R12 attn kv-split WIN (63->51.7); R19 gemm (256,4) + V^T uint2
// WIN (189.5->185.3); R21 XCD swizzle NEUTRAL; ping-pong x2, setprio,
// cvt_pk all FAIL. attn BANK_CONFLICT 4.19M = intrinsic b128 cost. attn
// frozen at R12 optimum (52.2us, WRITE exactly 8192 KB = clean).

typedef __bf16 bf16_t;
typedef __bf16 bf16x8 __attribute__((ext_vector_type(8)));
typedef float f32x4 __attribute__((ext_vector_type(4)));
typedef float f32x16 __attribute__((ext_vector_type(16)));
typedef unsigned u32x2 __attribute__((ext_vector_type(2)));

#define B_ 2
#define S_ 2048
#define D_ 1024
#define H_ 16
#define HD_ 64
// fold softmax scale (1/8) * log2(e) into Q so scores feed exp2 directly
#define QSCALE 0.18033688011112042f

__device__ __forceinline__ void load_lds16(const void* g, void* s) {
  // direct global->LDS DMA, 16B/lane; LDS dest is wave-uniform base + lane*16
  __builtin_amdgcn_global_load_lds((__attribute__((address_space(1))) unsigned int*)g,
                                   (__attribute__((address_space(3))) unsigned int*)s,
                                   16, 0, 0);
}

// fast fp32->bf16: round-to-nearest via +0x8000 (no NaN path; inputs finite).
__device__ __forceinline__ bf16_t fbf16(float x) {
  unsigned u = (__builtin_bit_cast(unsigned, x) + 0x8000u) >> 16;
  unsigned short s = (unsigned short)u;
  return __builtin_bit_cast(bf16_t, s);
}
// pack two fp32 -> bf16x2 in one v_perm_b32: result = {hi16(ub),hi16(ua)}
__device__ __forceinline__ unsigned pack_bf16x2(float a, float b) {
  unsigned ua = __builtin_bit_cast(unsigned, a) + 0x8000u;
  unsigned ub = __builtin_bit_cast(unsigned, b) + 0x8000u;
  return __builtin_amdgcn_perm(ub, ua, 0x07060302u);
}

// ---------------- fused fp32 -> bf16 convert (x, w_qkv, w_proj) ----------------
__global__ void tobf16_all(const float* __restrict__ x, const float* __restrict__ wq,
                           const float* __restrict__ wp, bf16_t* __restrict__ xb,
                           bf16_t* __restrict__ wqb, bf16_t* __restrict__ wpb) {
  int bid = blockIdx.x;
  const float* in;
  bf16_t* out;
  int base;
  if (bid < 4096) { in = x; out = xb; base = bid; }
  else if (bid < 7168) { in = wq; out = wqb; base = bid - 4096; }
  else { in = wp; out = wpb; base = bid - 7168; }
  int i = base * 256 + threadIdx.x;  // all three sizes are exact multiples of 256 float4
  float4 v = ((const float4*)in)[i];
  uint2 o;
  o.x = pack_bf16x2(v.x, v.y);
  o.y = pack_bf16x2(v.z, v.w);
  ((uint2*)out)[i] = o;
}

// ---------------- GEMM: C[M,N] = A[M,K] @ B[N,K]^T + bias ----------------
// 128xBN tile, BK=32, 256 threads (4 waves 2x2), TRIPLE-buffered with
// counted vmcnt + raw barrier (see file header). 16B-unit XOR swizzle.
// EPI=0: QKV epilogue (scatter to q/k/vT bf16 layouts, q pre-scaled), BN=128
// EPI=1: proj epilogue (fp32 out), BN=64 for 2x grid
template <int EPI, int BN>
__global__ __launch_bounds__(256, 3) void gemm_bt(
    const bf16_t* __restrict__ A, const bf16_t* __restrict__ Bm,
    const float* __restrict__ bias,
    bf16_t* __restrict__ qb, bf16_t* __restrict__ kb, bf16_t* __restrict__ vtb,
    float* __restrict__ outf) {
  constexpr int NI = BN / 32;            // n-fragments per wave
  constexpr int BUF = 8192 + BN * 64;    // bytes per buffer: A 8 KB + B BN*64
  // L = global_load_lds per thread per stage: A 2 + B BN/64. The ONLY vmem
  // ops inside the K-loop are stages, so vmcnt counts are exact.
  __shared__ __align__(16) char smem[3 * BUF];
  const int tid = threadIdx.x;
  const int w = tid >> 6, lane = tid & 63;
  const int wm = w >> 1, wn = w & 1;
  const int quad = lane >> 4, l15 = lane & 15;
  const int m0 = blockIdx.y * 128, n0 = blockIdx.x * BN;

  auto stage = [&](int kt, int bb) {
    char* bA = smem + bb * BUF;
    char* bB = bA + 8192;
#pragma unroll
    for (int i = 0; i < 2; i++) {  // A: 512 units
      int ub = w * 128 + i * 64;
      int u = ub + lane;
      int r = u >> 2, c = (u & 3) ^ ((r >> 1) & 3);
      load_lds16(A + (size_t)(m0 + r) * 1024 + kt + c * 8, bA + (size_t)ub * 16);
    }
#pragma unroll
    for (int i = 0; i < BN / 64; i++) {  // B: BN*4 units
      int ub = w * (BN / 64) * 64 + i * 64;
      int u = ub + lane;
      int r = u >> 2, c = (u & 3) ^ ((r >> 1) & 3);
      load_lds16(Bm + (size_t)(n0 + r) * 1024 + kt + c * 8, bB + (size_t)ub * 16);
    }
  };

  f32x4 acc[4][NI];
#pragma unroll
  for (int mi = 0; mi < 4; mi++)
#pragma unroll
    for (int ni = 0; ni < NI; ni++) acc[mi][ni] = (f32x4){0.f, 0.f, 0.f, 0.f};

  // one K-step: ds_read fragments from buffer bsel and run the MFMAs
  auto kstep = [&](int bsel) {
    const bf16_t* bA = (const bf16_t*)(smem + bsel * BUF);
    const bf16_t* bB = (const bf16_t*)(smem + bsel * BUF + 8192);
    bf16x8 af[4], bfr[NI];
#pragma unroll
    for (int mi = 0; mi < 4; mi++) {
      int r = wm * 64 + mi * 16 + l15;
      af[mi] = *(const bf16x8*)(bA + (r * 4 + (quad ^ ((r >> 1) & 3))) * 8);
    }
#pragma unroll
    for (int ni = 0; ni < NI; ni++) {
      int r = wn * (BN / 2) + ni * 16 + l15;
      bfr[ni] = *(const bf16x8*)(bB + (r * 4 + (quad ^ ((r >> 1) & 3))) * 8);
    }
#pragma unroll
    for (int mi = 0; mi < 4; mi++)
#pragma unroll
      for (int ni = 0; ni < NI; ni++)
        acc[mi][ni] = __builtin_amdgcn_mfma_f32_16x16x32_bf16(af[mi], bfr[ni], acc[mi][ni], 0, 0, 0);
  };

  // prologue: tiles 0 and 1 in flight (2L outstanding vmem ops)
  stage(0, 0);
  stage(32, 1);

  int b0 = 0, b1 = 1, b2 = 2;
  for (int it = 0; it < 31; ++it) {
    // drain stage(it) (oldest L), leave stage(it+1) in flight
    if constexpr (BN == 128)
      asm volatile("s_waitcnt vmcnt(4)" ::: "memory");
    else
      asm volatile("s_waitcnt vmcnt(3)" ::: "memory");
    __builtin_amdgcn_s_barrier();  // all waves drained their slice of tile it
    // buffer b2 = (it+2)%3 was last read at iter it-1; the barrier above
    // ordered those reads before these stores.
    if (it < 30) stage((it + 2) * 32, b2);
    kstep(b0);
    int t = b0; b0 = b1; b1 = b2; b2 = t;
  }
  // peeled iter 31: only stage(31) outstanding -> must fully drain
  asm volatile("s_waitcnt vmcnt(0)" ::: "memory");
  __builtin_amdgcn_s_barrier();
  kstep(b0);

  // epilogue: C row = m0+wm*64+mi*16+quad*4+r, col = n0+wn*(BN/2)+ni*16+l15
#pragma unroll
  for (int mi = 0; mi < 4; mi++) {
#pragma unroll
    for (int ni = 0; ni < NI; ni++) {
      int n = n0 + wn * (BN / 2) + ni * 16 + l15;
      float bv = bias[n];
      int mrow = m0 + wm * 64 + mi * 16 + quad * 4;  // 4 consecutive m
      if (EPI == 0) {
        int t = n >> 10;           // 0=Q,1=K,2=V (uniform per block: 128 | 1024)
        int rr = n & 1023;
        int hh = rr >> 6, d = rr & 63;
        int bb = mrow >> 11, s = mrow & 2047;  // all 4 rows share bb (m0%128==0)
        size_t bh = (size_t)(bb * H_ + hh);
        if (t == 2) {
          // V^T: per lane, 4 consecutive s at fixed d -> one 8B store
          uint2 o;
          o.x = pack_bf16x2(acc[mi][ni][0] + bv, acc[mi][ni][1] + bv);
          o.y = pack_bf16x2(acc[mi][ni][2] + bv, acc[mi][ni][3] + bv);
          *(uint2*)(vtb + (bh * HD_ + d) * S_ + s) = o;
        } else if (t == 0) {
#pragma unroll
          for (int r = 0; r < 4; r++)
            qb[(bh * S_ + s + r) * HD_ + d] = fbf16((acc[mi][ni][r] + bv) * QSCALE);
        } else {
#pragma unroll
          for (int r = 0; r < 4; r++)
            kb[(bh * S_ + s + r) * HD_ + d] = fbf16(acc[mi][ni][r] + bv);
        }
      } else {
#pragma unroll
        for (int r = 0; r < 4; r++)
          outf[(size_t)(mrow + r) * 1024 + n] = acc[mi][ni][r] + bv;
      }
    }
  }
}

// ---------------- flash attention (S^T form, kv-split, 2-stage pipelined) -------
// 1D grid of 1024; gid%8 = XCD: XCD g owns bh in [4g,4g+4) -> 2 MB K/V per XCD.
// block = (b,h, q-tile 64), 256 threads = 4 waves:
//   wave w: q-band (w&1)*32, kv-half (w>>1)*1024.  Each pair (waves 2p,2p+1)
//   runs its own dbuf pipeline over 32 kv-tiles of 32 (16 KB LDS per pair).
// S^T = K Q^T: A = K rows (m=kv 0..31, LDS), B = Q rows (n=q, regs).
// C/D 32x32: col=lane&31=q, row=kv=(reg&3)+8*(reg>>2)+4*h2  [m74/m101 layout].
// PIPELINE: iter j holds S_cur=S(j); av(j) read PRE-barrier (protects regs
// from stage(j+2) -> buf j&1), then barrier, stage(j+2), ak(j+1) reads +
// S(j+1) MFMAs | softmax(j) | PV(j). Single body, s_cur=s_next copy (~16
// v_mov, measured cheaper than every alternative tried).
// Max-free softmax => pair partials (O^T, l) combine by addition via LDS.
__global__ __launch_bounds__(256, 4) void attn(
    const bf16_t* __restrict__ qb, const bf16_t* __restrict__ kb,
    const bf16_t* __restrict__ vtb, bf16_t* __restrict__ ob) {
  __shared__ __align__(16) char smem[32768];
  const int tid = threadIdx.x, w = tid >> 6, lane = tid & 63;
  const int h2 = lane >> 5, l31 = lane & 31;
  const int qband = w & 1, pair = w >> 1;
  // XCD-aware decode: gid%8 = XCD; 4 bh x 32 q-tiles per XCD.
  const int gid = blockIdx.x;
  const int g = gid & 7, k_ = gid >> 3;
  const int bh = g * 4 + (k_ >> 5);
  const int qt = k_ & 31;
  const int b = bh >> 4, h = bh & 15;
  const size_t base = (size_t)bh * S_ * HD_;
  const size_t vbase = (size_t)bh * HD_ * S_;
  const int q0 = qt * 64;
  const int myq = q0 + qband * 32 + l31;  // this lane's q column
  const int kvbase = pair << 10;          // this wave's kv-half
  char* pbase = smem + pair * 16384;      // per-pair LDS: 2 bufs x (K 4K | V 4K)

  // Q B-frags (loop-invariant): B[n=q=l31][k=ks*16+h2*8+j]
  bf16x8 bq[4];
#pragma unroll
  for (int ks = 0; ks < 4; ks++)
    bq[ks] = *(const bf16x8*)(qb + base + (size_t)myq * 64 + ks * 16 + h2 * 8);

  // stage K[32 kv x 64 d] + V^T[64 d x 32 kv] into pair buffer bb.
  // K rows: 8 units/row, sigma(r)=r&7. V rows: 4 units/row, sigma(r)=(r>>1)&3.
  auto stage = [&](int kv0, int bb) {
    char* bK = pbase + bb * 8192;
    char* bV = bK + 4096;
#pragma unroll
    for (int i = 0; i < 2; i++) {
      int ub = qband * 64 + i * 128;
      int u = ub + lane;
      {
        int r = u >> 3, c = (u & 7) ^ (r & 7);
        load_lds16(kb + base + (size_t)(kv0 + r) * 64 + c * 8, bK + (size_t)ub * 16);
      }
      {
        int r = u >> 2, c = (u & 3) ^ ((r >> 1) & 3);
        load_lds16(vtb + vbase + (size_t)r * S_ + kv0 + c * 8, bV + (size_t)ub * 16);
      }
    }
  };

  f32x16 acc_o[2];
#pragma unroll
  for (int dt = 0; dt < 2; dt++)
#pragma unroll
    for (int i = 0; i < 16; i++) acc_o[dt][i] = 0.f;
  float l_acc = 0.f;  // per-lane: sum of p over this lane's kv rows, for q=myq

  // prologue: tile 0 staged+drained; tile 1 DMA in flight; s_cur = S(0)
  stage(kvbase, 0);
  __syncthreads();
  stage(kvbase + 32, 1);
  f32x16 s_cur;
  {
    const bf16_t* bK = (const bf16_t*)pbase;
#pragma unroll
    for (int i = 0; i < 16; i++) s_cur[i] = 0.f;
#pragma unroll
    for (int ks = 0; ks < 4; ks++) {
      int r = l31, c = ks * 2 + h2;
      bf16x8 ak = *(const bf16x8*)(bK + (r * 8 + (c ^ (r & 7))) * 8);
      s_cur = __builtin_amdgcn_mfma_f32_32x32x16_bf16(ak, bq[ks], s_cur, 0, 0, 0);
    }
  }

  for (int j = 0; j < 32; j++) {
    // V^T(j) A-frags PRE-barrier: tile j was drained at the previous barrier;
    // regs protect against stage(j+2) overwriting buf j&1 mid-iter.
    const bf16_t* bV = (const bf16_t*)(pbase + (j & 1) * 8192 + 4096);
    bf16x8 av[2][2];
#pragma unroll
    for (int ks = 0; ks < 2; ks++)
#pragma unroll
      for (int dt = 0; dt < 2; dt++) {
        int r = dt * 32 + l31, c = ks * 2 + h2;
        av[dt][ks] = *(const bf16x8*)(bV + (r * 4 + (c ^ ((r >> 1) & 3))) * 8);
      }

    __syncthreads();  // drains stage(j+1) DMA; all waves' av(j)/ak(j) reads done
    if (j < 30) stage(kvbase + (j + 2) * 32, j & 1);

    // S(j+1) = K(j+1) Q^T — independent of softmax(j) and PV(j)
    f32x16 s_next;
    if (j < 31) {
      const bf16_t* bK1 = (const bf16_t*)(pbase + ((j + 1) & 1) * 8192);
#pragma unroll
      for (int i = 0; i < 16; i++) s_next[i] = 0.f;
#pragma unroll
      for (int ks = 0; ks < 4; ks++) {
        int r = l31, c = ks * 2 + h2;
        bf16x8 ak = *(const bf16x8*)(bK1 + (r * 8 + (c ^ (r & 7))) * 8);
        s_next = __builtin_amdgcn_mfma_f32_32x32x16_bf16(ak, bq[ks], s_next, 0, 0, 0);
      }
    }

    // no-max softmax on s_cur (native exp2) + pack reg-pairs (adjacent kv)
    unsigned pk[8];
    float ls = 0.f;
#pragma unroll
    for (int i = 0; i < 8; i++) {
      float p0 = __builtin_amdgcn_exp2f(s_cur[2 * i]);
      float p1 = __builtin_amdgcn_exp2f(s_cur[2 * i + 1]);
      ls += p0 + p1;
      pk[i] = pack_bf16x2(p0, p1);
    }
    l_acc += ls;

    // build P^T B-frags: per 16-kv step, exchange packs across lane-halves.
    // permlane32_swap(a,b): dst0 = {a_lo | b_lo->hi}, dst1 = {a_hi->lo | b_hi}
    bf16x8 bp[2];
#pragma unroll
    for (int kk = 0; kk < 2; kk++) {
      unsigned a0 = pk[kk * 4 + 0], a1 = pk[kk * 4 + 1];
      unsigned a2 = pk[kk * 4 + 2], a3 = pk[kk * 4 + 3];
      u32x2 r02 = __builtin_amdgcn_permlane32_swap(a0, a2, false, false);
      u32x2 r13 = __builtin_amdgcn_permlane32_swap(a1, a3, false, false);
      union { unsigned u[4]; bf16x8 v; } bb;
      bb.u[0] = r02[0];
      bb.u[1] = r13[0];
      bb.u[2] = r02[1];
      bb.u[3] = r13[1];
      bp[kk] = bb.v;
    }

    // O^T += V^T(j) P^T(j)
#pragma unroll
    for (int ks = 0; ks < 2; ks++)
#pragma unroll
      for (int dt = 0; dt < 2; dt++)
        acc_o[dt] = __builtin_amdgcn_mfma_f32_32x32x16_bf16(av[dt][ks], bp[ks], acc_o[dt], 0, 0, 0);

    if (j < 31) s_cur = s_next;
  }

  // within-pair denominator: lane + h2-partner cover all kv rows of this half
  float l_pair = l_acc + (float)__shfl_xor(l_acc, 32);

  // cross-pair combine via LDS (K/V buffers dead after last in-loop barrier).
  // stride 33 floats -> conflict-free. Region: 2 qbands x 64 lanes x 33 f32.
  float* red = (float*)smem;
  const int rbase = qband * (64 * 33) + lane * 33;
  if (pair == 1) {
#pragma unroll
    for (int dt = 0; dt < 2; dt++)
#pragma unroll
      for (int i = 0; i < 16; i++) red[rbase + dt * 16 + i] = acc_o[dt][i];
    red[rbase + 32] = l_pair;
  }
  __syncthreads();
  if (pair == 0) {
#pragma unroll
    for (int dt = 0; dt < 2; dt++)
#pragma unroll
      for (int i = 0; i < 16; i++) acc_o[dt][i] += red[rbase + dt * 16 + i];
    float inv = 1.0f / (l_pair + red[rbase + 32]);

    // epilogue: O^T col q = myq (lane), rows d = dt*32 + 8*g4 + 4*h2 + (0..3)
#pragma unroll
    for (int dt = 0; dt < 2; dt++)
#pragma unroll
      for (int g4 = 0; g4 < 4; g4++) {
        uint2 o;
        o.x = pack_bf16x2(acc_o[dt][g4 * 4 + 0] * inv, acc_o[dt][g4 * 4 + 1] * inv);
        o.y = pack_bf16x2(acc_o[dt][g4 * 4 + 2] * inv, acc_o[dt][g4 * 4 + 3] * inv);
        int d = dt * 32 + g4 * 8 + h2 * 4;
        *(uint2*)(ob + ((size_t)b * S_ + myq) * D_ + h * HD_ + d) = o;
      }
  }
}

// ---------------- launcher ----------------
extern "C" void kernel_launch(void* const* d_in, const int* in_sizes, int n_in,
                              void* d_out, int out_size, void* d_ws, size_t ws_size,
                              hipStream_t stream) {
  const float* x = (const float*)d_in[0];        // [2,2048,1024]
  const float* w_qkv = (const float*)d_in[1];    // [3072,1024]
  const float* b_qkv = (const float*)d_in[2];    // [3072]
  const float* w_proj = (const float*)d_in[3];   // [1024,1024]
  const float* b_proj = (const float*)d_in[4];   // [1024]
  float* out = (float*)d_out;

  char* ws = (char*)d_ws;
  size_t off = 0;
  bf16_t* xb = (bf16_t*)(ws + off); off += (size_t)4096 * 1024 * 2;    // 8 MB
  bf16_t* wqkvb = (bf16_t*)(ws + off); off += (size_t)3072 * 1024 * 2; // 6 MB
  bf16_t* wpb = (bf16_t*)(ws + off); off += (size_t)1024 * 1024 * 2;   // 2 MB
  bf16_t* qb = (bf16_t*)(ws + off); off += (size_t)4096 * 1024 * 2;    // 8 MB [B,H,S,hd]
  bf16_t* kb = (bf16_t*)(ws + off); off += (size_t)4096 * 1024 * 2;    // 8 MB [B,H,S,hd]
  bf16_t* vtb = (bf16_t*)(ws + off); off += (size_t)4096 * 1024 * 2;   // 8 MB [B,H,hd,S]
  bf16_t* ob = xb;  // xb dead after QKV GEMM; reuse for attention output
  // total ws use: 41,943,040 B

  tobf16_all<<<8192, 256, 0, stream>>>(x, w_qkv, w_proj, xb, wqkvb, wpb);
  gemm_bt<0, 128><<<dim3(24, 32), 256, 0, stream>>>(xb, wqkvb, b_qkv, qb, kb, vtb, nullptr);
  attn<<<1024, 256, 0, stream>>>(qb, kb, vtb, ob);
  gemm_bt<1, 64><<<dim3(16, 32), 256, 0, stream>>>(ob, wpb, b_proj, nullptr, nullptr, nullptr, out);
}